// Round 6
// baseline (2195.480 us; speedup 1.0000x reference)
//
#include <hip/hip_runtime.h>
#include <math.h>

#define Bn 16
#define Tn 16384
#define Fn 32
#define Cn 64
#define Ln 10
#define ST 76   // LDS tile row stride (elements): 152B -> conflict-free patterns

typedef _Float16 v8h  __attribute__((ext_vector_type(8)));
typedef _Float16 v4h  __attribute__((ext_vector_type(4)));
typedef float    v16f __attribute__((ext_vector_type(16)));
typedef float    v4f  __attribute__((ext_vector_type(4)));

// ---------------------------------------------------------------------------
// Software grid barrier (device-scope atomics).  Cooperative launch is NOT
// stream-capturable (R5 failure: kernel never ran), so we use a counter +
// generation word in d_ws, zeroed by hipMemsetAsync each launch.
// Deadlock-safe by arithmetic: launch_bounds(256,4) -> VGPR<=128 -> 16 wv/CU;
// LDS 38912B -> 4 blk/CU; capacity 1024 >= grid 512 -> all blocks resident.
// Cross-XCD visibility: __threadfence() (agent scope: L2 wb/inv) around
// agent-scope acquire/release atomics; __syncthreads drains wave stores.
// ---------------------------------------------------------------------------
__device__ __forceinline__ void gbarrier(unsigned* bar, unsigned nblk, unsigned phase)
{
    __syncthreads();
    if (threadIdx.x == 0) {
        __threadfence();
        unsigned prev = __hip_atomic_fetch_add(&bar[0], 1u, __ATOMIC_ACQ_REL,
                                               __HIP_MEMORY_SCOPE_AGENT);
        if (prev == nblk - 1u) {
            __hip_atomic_store(&bar[0], 0u, __ATOMIC_RELAXED, __HIP_MEMORY_SCOPE_AGENT);
            __hip_atomic_store(&bar[1], phase, __ATOMIC_RELEASE, __HIP_MEMORY_SCOPE_AGENT);
        } else {
            while (__hip_atomic_load(&bar[1], __ATOMIC_ACQUIRE,
                                     __HIP_MEMORY_SCOPE_AGENT) < phase)
                __builtin_amdgcn_s_sleep(2);
        }
        __threadfence();
    }
    __syncthreads();
}

// ---------------------------------------------------------------------------
// Fully-fused WaveNet, one normal kernel + software barriers.
//  - 512 blocks x 256 threads; block owns a 512-t span (4 tiles of 128t) in
//    one batch, XCD-sliced: block j of a batch -> XCD (j&7), identical slice
//    every layer -> layer-to-layer h round trips stay in the XCD's L2.
//  - skip accumulator lives in REGISTERS across all 10 layers (sk[4][2][4])
//    -> eliminates the 64MB/layer skip RMW (half of k_layer's HBM traffic).
//  - 10 gbarriers replace 10 kernel-launch drains; skip never touches HBM.
//  - last layer: hout write + R epilogue skipped (h dead after layer 10).
// mfma_f32_32x32x16_f16: A[m=lane&31][k=(lane>>5)*8+j], B[k][n=lane&31],
// D: col(n)=lane&31, row(m)=(reg&3)+8*(reg>>2)+4*(lane>>5).
// ---------------------------------------------------------------------------
__global__ __launch_bounds__(256, 4) void k_fused(
    const float* __restrict__ x,
    const float* __restrict__ w_in, const float* __restrict__ b_in,
    const float* __restrict__ fw,  const float* __restrict__ gw,
    const float* __restrict__ rw,  const float* __restrict__ sw,
    const float* __restrict__ fb,  const float* __restrict__ gb,
    const float* __restrict__ rb,  const float* __restrict__ sb,
    const float* __restrict__ ow1, const float* __restrict__ ob1,
    const float* __restrict__ ow2, const float* __restrict__ ob2,
    float* __restrict__ out,
    _Float16* __restrict__ hA, _Float16* __restrict__ hB,
    _Float16* __restrict__ wfgP, _Float16* __restrict__ rsP,
    unsigned* __restrict__ bar)
{
    __shared__ _Float16 SH[2 * 128 * ST];          // 38912B, multi-purpose
    _Float16* const P0 = SH;
    _Float16* const P1 = SH + 128 * ST;

    const int tid  = threadIdx.x;
    const int lane = tid & 63;
    const int wv   = tid >> 6;
    const int ch32 = wv & 1;
    const int ch   = ch32 * 32;         // co-half
    const int tb   = (wv >> 1) * 64;    // t-half within a 128-tile
    const int hl   = lane >> 5;
    const int ln31 = lane & 31;
    const int bb   = blockIdx.x >> 5;   // 32 blocks per batch
    const int j    = blockIdx.x & 31;
    const int tBase = ((j & 7) * 16 + (j >> 3) * 4) * 128;   // 512-t span
    const size_t hbase = (size_t)bb * Tn * 64;

    v8h zero8;
    #pragma unroll
    for (int z = 0; z < 8; ++z) zero8[z] = (_Float16)0.f;

    // coalesced tap staging: thread covers 4 x (tl, 8c) cells
    const int s_tl = tid >> 3;              // base row (0..31), rows step 32
    const int s_c  = (tid & 7) * 8;

    // ---- phase P: weight packing fp32 -> fp16 fragment order (grid-stride)
    {
        const int total1 = Ln * 24576;
        for (int gid = blockIdx.x * 256 + tid; gid < total1; gid += 512 * 256) {
            int l = gid / 24576, rem = gid % 24576;
            int chunk = rem >> 9, within = rem & 511;
            int ll = within >> 3, jj = within & 7;
            int c32 = chunk & 1, fg = (chunk >> 1) & 1;
            int kc = (chunk >> 2) & 3, tap = chunk >> 4;
            int co = c32 * 32 + (ll & 31);
            int ci = kc * 16 + (ll >> 5) * 8 + jj;
            const float* wsrc = fg ? gw : fw;
            wfgP[gid] = (_Float16)wsrc[((l * 64 + co) * 64 + ci) * 3 + tap];
        }
        const int total2 = Ln * 8192;
        for (int gid = blockIdx.x * 256 + tid; gid < total2; gid += 512 * 256) {
            int l = gid / 8192, rem = gid % 8192;
            int chunk = rem >> 9, within = rem & 511;
            int ll = within >> 3, jj = within & 7;
            int c32 = chunk & 1, rsi = (chunk >> 1) & 1, kc = chunk >> 2;
            int co = c32 * 32 + (ll & 31);
            int ci = kc * 16 + (ll >> 5) * 8 + jj;
            const float* wsrc = rsi ? sw : rw;
            rsP[gid] = (_Float16)wsrc[(l * 64 + co) * 64 + ci];
        }
    }

    // ---- phase I: input 1x1 conv -> hA for this block's 512 t.
    // One thread per t -> w_in/b_in loop-uniform -> scalar loads; stores
    // through LDS rotation -> flat contiguous global stores.
    #pragma unroll
    for (int u = 0; u < 2; ++u) {
        const int t0c = tBase + u * 256;
        const float* xp = x + ((size_t)bb * Tn + t0c + tid) * Fn;
        float xv[32];
        #pragma unroll
        for (int i = 0; i < 8; ++i) {
            v4f v = *(const v4f*)&xp[i * 4];
            xv[i*4+0] = v[0]; xv[i*4+1] = v[1]; xv[i*4+2] = v[2]; xv[i*4+3] = v[3];
        }
        #pragma unroll
        for (int c8 = 0; c8 < 8; ++c8) {
            v8h o;
            #pragma unroll
            for (int jj = 0; jj < 8; ++jj) {
                int c = c8 * 8 + jj;                // loop-uniform -> s_loads
                float a = b_in[c];
                #pragma unroll
                for (int f = 0; f < 32; ++f) a = fmaf(w_in[c * 32 + f], xv[f], a);
                o[jj] = (_Float16)a;
            }
            const int p = (c8 + tid) & 7;           // bank-rotate chunk slot
            *(v8h*)&SH[tid * 64 + p * 8] = o;
        }
        __syncthreads();
        _Float16* hp = hA + ((size_t)bb * Tn + t0c) * 64;
        #pragma unroll
        for (int it = 0; it < 8; ++it) {
            const int g = it * 256 + tid;           // flat 16B chunk index
            const int tl = g >> 3, c8 = g & 7;
            const int p = (c8 + tl) & 7;
            *(v8h*)&hp[g * 8] = *(const v8h*)&SH[tl * 64 + p * 8];
        }
        __syncthreads();
    }

    gbarrier(bar, 512, 1);                          // weights + h0 visible

    // persistent skip accumulator: [tile][nt][q] -> 16 VGPRs of fp16x4
    v4h sk[4][2][4];

    const _Float16* cur = hA;
    _Float16* nxt = hB;

#define STAGE(DST, OFF) do {                                                  \
    _Pragma("unroll")                                                         \
    for (int it = 0; it < 4; ++it) {                                          \
        int tl = s_tl + it * 32;                                              \
        int tg = t0 + tl - (OFF);                                             \
        v8h v = zero8;                                                        \
        if (tg >= 0) v = *(const v8h*)&cur[hbase + (size_t)tg * 64 + s_c];    \
        *(v8h*)&(DST)[tl * ST + s_c] = v;                                     \
    } } while (0)

#define WOFF(TAP, KC, FG) (((((TAP) * 4 + (KC)) * 2 + (FG)) * 2 + ch32) * 512 + lane * 8)
#define RSOFF(KC, RSI)    ((((KC) * 2 + (RSI)) * 2 + ch32) * 512 + lane * 8)

#define MFMA_TAP(SRC, TAP) do {                                               \
    _Pragma("unroll")                                                         \
    for (int kc = 0; kc < 4; ++kc) {                                          \
        const int kof = kc * 16 + hl * 8;                                     \
        v8h aF = *(const v8h*)&wfg[WOFF(TAP, kc, 0)];                         \
        v8h aG = *(const v8h*)&wfg[WOFF(TAP, kc, 1)];                         \
        v8h b0 = *(const v8h*)&(SRC)[(tb + ln31) * ST + kof];                 \
        v8h b1 = *(const v8h*)&(SRC)[(tb + 32 + ln31) * ST + kof];            \
        accF[0] = __builtin_amdgcn_mfma_f32_32x32x16_f16(aF, b0, accF[0], 0, 0, 0); \
        accF[1] = __builtin_amdgcn_mfma_f32_32x32x16_f16(aF, b1, accF[1], 0, 0, 0); \
        accG[0] = __builtin_amdgcn_mfma_f32_32x32x16_f16(aG, b0, accG[0], 0, 0, 0); \
        accG[1] = __builtin_amdgcn_mfma_f32_32x32x16_f16(aG, b1, accG[1], 0, 0, 0); \
    } } while (0)

    #pragma unroll 1
    for (int l = 0; l < Ln; ++l) {
        const int dil = 1 << l;
        const _Float16* wfg = wfgP + (size_t)l * 24576;
        const _Float16* rs  = rsP  + (size_t)l * 8192;
        const float* fbl = fb + l * Cn;
        const float* gbl = gb + l * Cn;
        const float* rbl = rb + l * Cn;
        const float* sbl = sb + l * Cn;
        const bool last = (l == Ln - 1);

        #pragma unroll
        for (int tile = 0; tile < 4; ++tile) {
            const int t0 = tBase + tile * 128;

            // biases -> accumulator init (D row m -> c = ch + 8q + 4hl + r)
            v16f accF[2], accG[2];
            #pragma unroll
            for (int q = 0; q < 4; ++q) {
                v4f fv = *(const v4f*)&fbl[ch + 8 * q + 4 * hl];
                v4f gv = *(const v4f*)&gbl[ch + 8 * q + 4 * hl];
                #pragma unroll
                for (int r = 0; r < 4; ++r) {
                    accF[0][q * 4 + r] = fv[r]; accF[1][q * 4 + r] = fv[r];
                    accG[0][q * 4 + r] = gv[r]; accG[1][q * 4 + r] = gv[r];
                }
            }

            STAGE(P0, 2 * dil);
            __syncthreads();                        // S1: P0 ready
            STAGE(P1, dil);                         // overlap tap1 loads w/ tap0 mfma
            MFMA_TAP(P0, 0);
            __syncthreads();                        // S2: P1 ready, P0 reads done
            STAGE(P0, 0);                           // overlap tap2 loads w/ tap1 mfma
            MFMA_TAP(P1, 1);
            __syncthreads();                        // S3: P0 ready, P1 reads done
            MFMA_TAP(P0, 2);                        // P0 holds hin[t] - kept

            // act = tanh(f)*sigmoid(g) = (A-1)*rcp((A+1)*(1+B)) -> P1 scatter
            #pragma unroll
            for (int nt = 0; nt < 2; ++nt) {
                const int tl = tb + nt * 32 + ln31;
                #pragma unroll
                for (int q = 0; q < 4; ++q) {
                    v4h av;
                    #pragma unroll
                    for (int r = 0; r < 4; ++r) {
                        float f = accF[nt][q * 4 + r];
                        float g = accG[nt][q * 4 + r];
                        float A = __expf(2.f * f);
                        float B = __expf(-g);
                        float tA = A + 1.f;
                        float den = fmaf(tA, B, tA);
                        av[r] = (_Float16)((A - 1.f) * __builtin_amdgcn_rcpf(den));
                    }
                    *(v4h*)&P1[tl * ST + ch + 8 * q + 4 * hl] = av;
                }
            }
            __syncthreads();                        // S4: act done, tap2 reads done

            v16f accR[2], accS[2];
            #pragma unroll
            for (int q = 0; q < 4; ++q) {
                v4f rv = *(const v4f*)&rbl[ch + 8 * q + 4 * hl];
                v4f sv = *(const v4f*)&sbl[ch + 8 * q + 4 * hl];
                #pragma unroll
                for (int r = 0; r < 4; ++r) {
                    accR[0][q * 4 + r] = rv[r]; accR[1][q * 4 + r] = rv[r];
                    accS[0][q * 4 + r] = sv[r]; accS[1][q * 4 + r] = sv[r];
                }
            }
            #pragma unroll
            for (int kc = 0; kc < 4; ++kc) {
                const int kof = kc * 16 + hl * 8;
                v8h aR = *(const v8h*)&rs[RSOFF(kc, 0)];
                v8h aS = *(const v8h*)&rs[RSOFF(kc, 1)];
                v8h b0 = *(const v8h*)&P1[(tb + ln31) * ST + kof];
                v8h b1 = *(const v8h*)&P1[(tb + 32 + ln31) * ST + kof];
                accR[0] = __builtin_amdgcn_mfma_f32_32x32x16_f16(aR, b0, accR[0], 0, 0, 0);
                accR[1] = __builtin_amdgcn_mfma_f32_32x32x16_f16(aR, b1, accR[1], 0, 0, 0);
                accS[0] = __builtin_amdgcn_mfma_f32_32x32x16_f16(aS, b0, accS[0], 0, 0, 0);
                accS[1] = __builtin_amdgcn_mfma_f32_32x32x16_f16(aS, b1, accS[1], 0, 0, 0);
            }

            // R epilogue in-place on P0: h_new = (h + R)*0.7071 (dead last layer)
            if (!last) {
                #pragma unroll
                for (int nt = 0; nt < 2; ++nt) {
                    const int tl = tb + nt * 32 + ln31;
                    #pragma unroll
                    for (int q = 0; q < 4; ++q) {
                        _Float16* cell = &P0[tl * ST + ch + 8 * q + 4 * hl];
                        v4h hv = *(const v4h*)cell;
                        v4h hn;
                        #pragma unroll
                        for (int r = 0; r < 4; ++r)
                            hn[r] = (_Float16)(((float)hv[r] + accR[nt][q * 4 + r]) * 0.7071f);
                        *(v4h*)cell = hn;
                    }
                }
            }

            // skip accumulation IN REGISTERS (no HBM RMW)
            #pragma unroll
            for (int nt = 0; nt < 2; ++nt)
                #pragma unroll
                for (int q = 0; q < 4; ++q) {
                    v4h sn;
                    #pragma unroll
                    for (int r = 0; r < 4; ++r) {
                        float v = accS[nt][q * 4 + r];
                        if (l) v += (float)sk[tile][nt][q][r];
                        sn[r] = (_Float16)v;
                    }
                    sk[tile][nt][q] = sn;
                }
            __syncthreads();                        // S5: P0 = hout tile complete

            // hout coalesced store from P0 (dead for last layer)
            if (!last) {
                #pragma unroll
                for (int it = 0; it < 4; ++it) {
                    int tl = s_tl + it * 32;
                    *(v8h*)&nxt[hbase + (size_t)(t0 + tl) * 64 + s_c] =
                        *(const v8h*)&P0[tl * ST + s_c];
                }
            }
            __syncthreads();                        // S6: P0/P1 reusable next tile
        }

        if (!last) {
            gbarrier(bar, 512, (unsigned)(l + 2));  // layer complete device-wide
            _Float16* tmp = nxt; nxt = (_Float16*)cur; cur = tmp;
        }
    }
#undef STAGE
#undef MFMA_TAP
#undef WOFF
#undef RSOFF

    // ---- phase O: skip regs -> LDS transpose -> 2-layer MLP -> out ----
    // Per pass: 2 tiles (256 t); SH stride 68 halfs breaks bank aliasing.
    #pragma unroll
    for (int u = 0; u < 2; ++u) {
        #pragma unroll
        for (int tl2 = 0; tl2 < 2; ++tl2) {
            const int tile = u * 2 + tl2;
            #pragma unroll
            for (int nt = 0; nt < 2; ++nt)
                #pragma unroll
                for (int q = 0; q < 4; ++q) {
                    const int row = tl2 * 128 + tb + nt * 32 + ln31;
                    *(v4h*)&SH[row * 68 + ch + 8 * q + 4 * hl] = sk[tile][nt][q];
                }
        }
        __syncthreads();
        const int t = tBase + u * 256 + tid;        // one t per thread
        float y[64];
        #pragma unroll
        for (int i = 0; i < 16; ++i) {
            v4h v = *(const v4h*)&SH[tid * 68 + i * 4];
            #pragma unroll
            for (int r = 0; r < 4; ++r) y[i * 4 + r] = fmaxf((float)v[r], 0.f);
        }
        float o = ob2[0];
        for (int co = 0; co < 64; ++co) {           // weights uniform -> s_loads
            float a0 = ob1[co], a1 = 0.f;
            #pragma unroll
            for (int ci = 0; ci < 64; ci += 2) {
                a0 = fmaf(ow1[co * 64 + ci],     y[ci],     a0);
                a1 = fmaf(ow1[co * 64 + ci + 1], y[ci + 1], a1);
            }
            o = fmaf(ow2[co], fmaxf(a0 + a1, 0.f), o);
        }
        out[(size_t)bb * Tn + t] = o;
        __syncthreads();                            // SH reusable for u=1
    }
}

// ---------------------------------------------------------------------------
extern "C" void kernel_launch(void* const* d_in, const int* in_sizes, int n_in,
                              void* d_out, int out_size, void* d_ws, size_t ws_size,
                              hipStream_t stream)
{
    const float* x    = (const float*)d_in[0];
    const float* w_in = (const float*)d_in[1];
    const float* b_in = (const float*)d_in[2];
    const float* fw   = (const float*)d_in[3];
    const float* fb   = (const float*)d_in[4];
    const float* gw   = (const float*)d_in[5];
    const float* gb   = (const float*)d_in[6];
    const float* rw   = (const float*)d_in[7];
    const float* rb   = (const float*)d_in[8];
    const float* sw   = (const float*)d_in[9];
    const float* sb   = (const float*)d_in[10];
    const float* ow1  = (const float*)d_in[11];
    const float* ob1  = (const float*)d_in[12];
    const float* ow2  = (const float*)d_in[13];
    const float* ob2  = (const float*)d_in[14];
    float* out = (float*)d_out;

    const size_t n = (size_t)Bn * Tn * 64;
    _Float16* hA   = (_Float16*)d_ws;
    _Float16* hB   = hA + n;
    _Float16* wfgP = hB + n;
    _Float16* rsP  = wfgP + (size_t)Ln * 24576;
    unsigned* bar  = (unsigned*)(rsP + (size_t)Ln * 8192);

    hipMemsetAsync(bar, 0, 2 * sizeof(unsigned), stream);
    k_fused<<<dim3(512), dim3(256), 0, stream>>>(
        x, w_in, b_in, fw, gw, rw, sw, fb, gb, rb, sb,
        ow1, ob1, ow2, ob2, out, hA, hB, wfgP, rsP, bar);
}

// Round 9
// 2021.950 us; speedup vs baseline: 1.0858x; 1.0858x over previous
//
#include <hip/hip_runtime.h>
#include <math.h>

#define Bn 16
#define Tn 16384
#define Fn 32
#define Cn 64
#define Ln 10
#define ST 76   // LDS tile row stride (elements): 152B -> conflict-free patterns

typedef _Float16 v8h  __attribute__((ext_vector_type(8)));
typedef _Float16 v4h  __attribute__((ext_vector_type(4)));
typedef float    v16f __attribute__((ext_vector_type(16)));
typedef float    v4f  __attribute__((ext_vector_type(4)));

// ---------------------------------------------------------------------------
// Software grid barrier (device-scope atomics).  Cooperative launch is NOT
// stream-capturable (R5), so: counter + generation word in d_ws, zeroed by
// hipMemsetAsync each launch.
// Deadlock-safe by arithmetic: launch_bounds(256,2) -> VGPR<=256 -> 8 wv/CU
// -> 2 blk/CU; LDS 38912B -> 4 blk/CU; capacity min(2,4)*256 = 512 >= grid
// 512 -> all blocks resident.  R6 lesson: (256,4) capped VGPR at 128 and the
// compiler SPILLED the persistent skip accumulator to scratch (VGPR_Count=64,
// 3.0GB HBM traffic, 2.2ms).  The fusion needs the 256-VGPR budget.
// Cross-XCD visibility: __threadfence() (agent scope) around agent-scope
// acquire/release atomics; __syncthreads drains wave stores.
// ---------------------------------------------------------------------------
__device__ __forceinline__ void gbarrier(unsigned* bar, unsigned nblk, unsigned phase)
{
    __syncthreads();
    if (threadIdx.x == 0) {
        __threadfence();
        unsigned prev = __hip_atomic_fetch_add(&bar[0], 1u, __ATOMIC_ACQ_REL,
                                               __HIP_MEMORY_SCOPE_AGENT);
        if (prev == nblk - 1u) {
            __hip_atomic_store(&bar[0], 0u, __ATOMIC_RELAXED, __HIP_MEMORY_SCOPE_AGENT);
            __hip_atomic_store(&bar[1], phase, __ATOMIC_RELEASE, __HIP_MEMORY_SCOPE_AGENT);
        } else {
            while (__hip_atomic_load(&bar[1], __ATOMIC_ACQUIRE,
                                     __HIP_MEMORY_SCOPE_AGENT) < phase)
                __builtin_amdgcn_s_sleep(2);
        }
        __threadfence();
    }
    __syncthreads();
}

// ---------------------------------------------------------------------------
// Fully-fused WaveNet, one normal kernel + software barriers.
//  - 512 blocks x 256 threads; block owns a 512-t span (4 tiles of 128t) in
//    one batch, XCD-sliced: block j of a batch -> XCD (j&7), identical slice
//    every layer -> layer-to-layer h round trips stay in the XCD's L2.
//  - skip accumulator lives in REGISTERS across all 10 layers (sk[4][2][4])
//    -> eliminates the 64MB/layer skip RMW (half of R3's k_layer HBM traffic).
//  - 10 gbarriers replace 10 kernel-launch drains; skip never touches HBM.
//  - last layer: hout write + R epilogue skipped (h dead after layer 10).
// mfma_f32_32x32x16_f16: A[m=lane&31][k=(lane>>5)*8+j], B[k][n=lane&31],
// D: col(n)=lane&31, row(m)=(reg&3)+8*(reg>>2)+4*(lane>>5).
// ---------------------------------------------------------------------------
__global__ __launch_bounds__(256, 2) void k_fused(
    const float* __restrict__ x,
    const float* __restrict__ w_in, const float* __restrict__ b_in,
    const float* __restrict__ fw,  const float* __restrict__ gw,
    const float* __restrict__ rw,  const float* __restrict__ sw,
    const float* __restrict__ fb,  const float* __restrict__ gb,
    const float* __restrict__ rb,  const float* __restrict__ sb,
    const float* __restrict__ ow1, const float* __restrict__ ob1,
    const float* __restrict__ ow2, const float* __restrict__ ob2,
    float* __restrict__ out,
    _Float16* __restrict__ hA, _Float16* __restrict__ hB,
    _Float16* __restrict__ wfgP, _Float16* __restrict__ rsP,
    unsigned* __restrict__ bar)
{
    __shared__ _Float16 SH[2 * 128 * ST];          // 38912B, multi-purpose
    _Float16* const P0 = SH;
    _Float16* const P1 = SH + 128 * ST;

    const int tid  = threadIdx.x;
    const int lane = tid & 63;
    const int wv   = tid >> 6;
    const int ch32 = wv & 1;
    const int ch   = ch32 * 32;         // co-half
    const int tb   = (wv >> 1) * 64;    // t-half within a 128-tile
    const int hl   = lane >> 5;
    const int ln31 = lane & 31;
    const int bb   = blockIdx.x >> 5;   // 32 blocks per batch
    const int j    = blockIdx.x & 31;
    const int tBase = ((j & 7) * 16 + (j >> 3) * 4) * 128;   // 512-t span
    const size_t hbase = (size_t)bb * Tn * 64;

    v8h zero8;
    #pragma unroll
    for (int z = 0; z < 8; ++z) zero8[z] = (_Float16)0.f;

    // coalesced tap staging: thread covers 4 x (tl, 8c) cells
    const int s_tl = tid >> 3;              // base row (0..31), rows step 32
    const int s_c  = (tid & 7) * 8;

    // ---- phase P: weight packing fp32 -> fp16 fragment order (grid-stride)
    {
        const int total1 = Ln * 24576;
        for (int gid = blockIdx.x * 256 + tid; gid < total1; gid += 512 * 256) {
            int l = gid / 24576, rem = gid % 24576;
            int chunk = rem >> 9, within = rem & 511;
            int ll = within >> 3, jj = within & 7;
            int c32 = chunk & 1, fg = (chunk >> 1) & 1;
            int kc = (chunk >> 2) & 3, tap = chunk >> 4;
            int co = c32 * 32 + (ll & 31);
            int ci = kc * 16 + (ll >> 5) * 8 + jj;
            const float* wsrc = fg ? gw : fw;
            wfgP[gid] = (_Float16)wsrc[((l * 64 + co) * 64 + ci) * 3 + tap];
        }
        const int total2 = Ln * 8192;
        for (int gid = blockIdx.x * 256 + tid; gid < total2; gid += 512 * 256) {
            int l = gid / 8192, rem = gid % 8192;
            int chunk = rem >> 9, within = rem & 511;
            int ll = within >> 3, jj = within & 7;
            int c32 = chunk & 1, rsi = (chunk >> 1) & 1, kc = chunk >> 2;
            int co = c32 * 32 + (ll & 31);
            int ci = kc * 16 + (ll >> 5) * 8 + jj;
            const float* wsrc = rsi ? sw : rw;
            rsP[gid] = (_Float16)wsrc[(l * 64 + co) * 64 + ci];
        }
    }

    // ---- phase I: input 1x1 conv -> hA for this block's 512 t.
    // One thread per t -> w_in/b_in loop-uniform -> scalar loads; stores
    // through LDS rotation -> flat contiguous global stores.
    #pragma unroll
    for (int u = 0; u < 2; ++u) {
        const int t0c = tBase + u * 256;
        const float* xp = x + ((size_t)bb * Tn + t0c + tid) * Fn;
        float xv[32];
        #pragma unroll
        for (int i = 0; i < 8; ++i) {
            v4f v = *(const v4f*)&xp[i * 4];
            xv[i*4+0] = v[0]; xv[i*4+1] = v[1]; xv[i*4+2] = v[2]; xv[i*4+3] = v[3];
        }
        #pragma unroll
        for (int c8 = 0; c8 < 8; ++c8) {
            v8h o;
            #pragma unroll
            for (int jj = 0; jj < 8; ++jj) {
                int c = c8 * 8 + jj;                // loop-uniform -> s_loads
                float a = b_in[c];
                #pragma unroll
                for (int f = 0; f < 32; ++f) a = fmaf(w_in[c * 32 + f], xv[f], a);
                o[jj] = (_Float16)a;
            }
            const int p = (c8 + tid) & 7;           // bank-rotate chunk slot
            *(v8h*)&SH[tid * 64 + p * 8] = o;
        }
        __syncthreads();
        _Float16* hp = hA + ((size_t)bb * Tn + t0c) * 64;
        #pragma unroll
        for (int it = 0; it < 8; ++it) {
            const int g = it * 256 + tid;           // flat 16B chunk index
            const int tl = g >> 3, c8 = g & 7;
            const int p = (c8 + tl) & 7;
            *(v8h*)&hp[g * 8] = *(const v8h*)&SH[tl * 64 + p * 8];
        }
        __syncthreads();
    }

    gbarrier(bar, 512, 1);                          // weights + h0 visible

    // persistent skip accumulator: [tile][nt][q], static-indexed -> 64 VGPRs
    v4h sk[4][2][4];

    const _Float16* cur = hA;
    _Float16* nxt = hB;

#define STAGE(DST, OFF) do {                                                  \
    _Pragma("unroll")                                                         \
    for (int it = 0; it < 4; ++it) {                                          \
        int tl = s_tl + it * 32;                                              \
        int tg = t0 + tl - (OFF);                                             \
        v8h v = zero8;                                                        \
        if (tg >= 0) v = *(const v8h*)&cur[hbase + (size_t)tg * 64 + s_c];    \
        *(v8h*)&(DST)[tl * ST + s_c] = v;                                     \
    } } while (0)

#define WOFF(TAP, KC, FG) (((((TAP) * 4 + (KC)) * 2 + (FG)) * 2 + ch32) * 512 + lane * 8)
#define RSOFF(KC, RSI)    ((((KC) * 2 + (RSI)) * 2 + ch32) * 512 + lane * 8)

#define MFMA_TAP(SRC, TAP) do {                                               \
    _Pragma("unroll")                                                         \
    for (int kc = 0; kc < 4; ++kc) {                                          \
        const int kof = kc * 16 + hl * 8;                                     \
        v8h aF = *(const v8h*)&wfg[WOFF(TAP, kc, 0)];                         \
        v8h aG = *(const v8h*)&wfg[WOFF(TAP, kc, 1)];                         \
        v8h b0 = *(const v8h*)&(SRC)[(tb + ln31) * ST + kof];                 \
        v8h b1 = *(const v8h*)&(SRC)[(tb + 32 + ln31) * ST + kof];            \
        accF[0] = __builtin_amdgcn_mfma_f32_32x32x16_f16(aF, b0, accF[0], 0, 0, 0); \
        accF[1] = __builtin_amdgcn_mfma_f32_32x32x16_f16(aF, b1, accF[1], 0, 0, 0); \
        accG[0] = __builtin_amdgcn_mfma_f32_32x32x16_f16(aG, b0, accG[0], 0, 0, 0); \
        accG[1] = __builtin_amdgcn_mfma_f32_32x32x16_f16(aG, b1, accG[1], 0, 0, 0); \
    } } while (0)

    #pragma unroll 1
    for (int l = 0; l < Ln; ++l) {
        const int dil = 1 << l;
        const _Float16* wfg = wfgP + (size_t)l * 24576;
        const _Float16* rs  = rsP  + (size_t)l * 8192;
        const float* fbl = fb + l * Cn;
        const float* gbl = gb + l * Cn;
        const float* rbl = rb + l * Cn;
        const float* sbl = sb + l * Cn;
        const bool last = (l == Ln - 1);

        #pragma unroll
        for (int tile = 0; tile < 4; ++tile) {
            const int t0 = tBase + tile * 128;

            // biases -> accumulator init (D row m -> c = ch + 8q + 4hl + r)
            v16f accF[2], accG[2];
            #pragma unroll
            for (int q = 0; q < 4; ++q) {
                v4f fv = *(const v4f*)&fbl[ch + 8 * q + 4 * hl];
                v4f gv = *(const v4f*)&gbl[ch + 8 * q + 4 * hl];
                #pragma unroll
                for (int r = 0; r < 4; ++r) {
                    accF[0][q * 4 + r] = fv[r]; accF[1][q * 4 + r] = fv[r];
                    accG[0][q * 4 + r] = gv[r]; accG[1][q * 4 + r] = gv[r];
                }
            }

            STAGE(P0, 2 * dil);
            __syncthreads();                        // S1: P0 ready
            STAGE(P1, dil);                         // overlap tap1 loads w/ tap0 mfma
            MFMA_TAP(P0, 0);
            __syncthreads();                        // S2: P1 ready, P0 reads done
            STAGE(P0, 0);                           // overlap tap2 loads w/ tap1 mfma
            MFMA_TAP(P1, 1);
            __syncthreads();                        // S3: P0 ready, P1 reads done
            MFMA_TAP(P0, 2);                        // P0 holds hin[t] - kept

            // act = tanh(f)*sigmoid(g) = (A-1)*rcp((A+1)*(1+B)) -> P1 scatter
            #pragma unroll
            for (int nt = 0; nt < 2; ++nt) {
                const int tl = tb + nt * 32 + ln31;
                #pragma unroll
                for (int q = 0; q < 4; ++q) {
                    v4h av;
                    #pragma unroll
                    for (int r = 0; r < 4; ++r) {
                        float f = accF[nt][q * 4 + r];
                        float g = accG[nt][q * 4 + r];
                        float A = __expf(2.f * f);
                        float B = __expf(-g);
                        float tA = A + 1.f;
                        float den = fmaf(tA, B, tA);
                        av[r] = (_Float16)((A - 1.f) * __builtin_amdgcn_rcpf(den));
                    }
                    *(v4h*)&P1[tl * ST + ch + 8 * q + 4 * hl] = av;
                }
            }
            __syncthreads();                        // S4: act done, tap2 reads done

            v16f accR[2], accS[2];
            #pragma unroll
            for (int q = 0; q < 4; ++q) {
                v4f rv = *(const v4f*)&rbl[ch + 8 * q + 4 * hl];
                v4f sv = *(const v4f*)&sbl[ch + 8 * q + 4 * hl];
                #pragma unroll
                for (int r = 0; r < 4; ++r) {
                    accR[0][q * 4 + r] = rv[r]; accR[1][q * 4 + r] = rv[r];
                    accS[0][q * 4 + r] = sv[r]; accS[1][q * 4 + r] = sv[r];
                }
            }
            #pragma unroll
            for (int kc = 0; kc < 4; ++kc) {
                const int kof = kc * 16 + hl * 8;
                v8h aR = *(const v8h*)&rs[RSOFF(kc, 0)];
                v8h aS = *(const v8h*)&rs[RSOFF(kc, 1)];
                v8h b0 = *(const v8h*)&P1[(tb + ln31) * ST + kof];
                v8h b1 = *(const v8h*)&P1[(tb + 32 + ln31) * ST + kof];
                accR[0] = __builtin_amdgcn_mfma_f32_32x32x16_f16(aR, b0, accR[0], 0, 0, 0);
                accR[1] = __builtin_amdgcn_mfma_f32_32x32x16_f16(aR, b1, accR[1], 0, 0, 0);
                accS[0] = __builtin_amdgcn_mfma_f32_32x32x16_f16(aS, b0, accS[0], 0, 0, 0);
                accS[1] = __builtin_amdgcn_mfma_f32_32x32x16_f16(aS, b1, accS[1], 0, 0, 0);
            }

            // R epilogue in-place on P0: h_new = (h + R)*0.7071 (dead last layer)
            if (!last) {
                #pragma unroll
                for (int nt = 0; nt < 2; ++nt) {
                    const int tl = tb + nt * 32 + ln31;
                    #pragma unroll
                    for (int q = 0; q < 4; ++q) {
                        _Float16* cell = &P0[tl * ST + ch + 8 * q + 4 * hl];
                        v4h hv = *(const v4h*)cell;
                        v4h hn;
                        #pragma unroll
                        for (int r = 0; r < 4; ++r)
                            hn[r] = (_Float16)(((float)hv[r] + accR[nt][q * 4 + r]) * 0.7071f);
                        *(v4h*)cell = hn;
                    }
                }
            }

            // skip accumulation IN REGISTERS (no HBM RMW)
            #pragma unroll
            for (int nt = 0; nt < 2; ++nt)
                #pragma unroll
                for (int q = 0; q < 4; ++q) {
                    v4h sn;
                    #pragma unroll
                    for (int r = 0; r < 4; ++r) {
                        float v = accS[nt][q * 4 + r];
                        if (l) v += (float)sk[tile][nt][q][r];
                        sn[r] = (_Float16)v;
                    }
                    sk[tile][nt][q] = sn;
                }
            __syncthreads();                        // S5: P0 = hout tile complete

            // hout coalesced store from P0 (dead for last layer)
            if (!last) {
                #pragma unroll
                for (int it = 0; it < 4; ++it) {
                    int tl = s_tl + it * 32;
                    *(v8h*)&nxt[hbase + (size_t)(t0 + tl) * 64 + s_c] =
                        *(const v8h*)&P0[tl * ST + s_c];
                }
            }
            __syncthreads();                        // S6: P0/P1 reusable next tile
        }

        if (!last) {
            gbarrier(bar, 512, (unsigned)(l + 2));  // layer complete device-wide
            _Float16* tmp = nxt; nxt = (_Float16*)cur; cur = tmp;
        }
    }
#undef STAGE
#undef MFMA_TAP
#undef WOFF
#undef RSOFF

    // ---- phase O: skip regs -> LDS transpose -> 2-layer MLP -> out ----
    // Per pass: 2 tiles (256 t); SH stride 68 halfs breaks bank aliasing.
    #pragma unroll
    for (int u = 0; u < 2; ++u) {
        #pragma unroll
        for (int tl2 = 0; tl2 < 2; ++tl2) {
            const int tile = u * 2 + tl2;
            #pragma unroll
            for (int nt = 0; nt < 2; ++nt)
                #pragma unroll
                for (int q = 0; q < 4; ++q) {
                    const int row = tl2 * 128 + tb + nt * 32 + ln31;
                    *(v4h*)&SH[row * 68 + ch + 8 * q + 4 * hl] = sk[tile][nt][q];
                }
        }
        __syncthreads();
        const int t = tBase + u * 256 + tid;        // one t per thread
        float y[64];
        #pragma unroll
        for (int i = 0; i < 16; ++i) {
            v4h v = *(const v4h*)&SH[tid * 68 + i * 4];
            #pragma unroll
            for (int r = 0; r < 4; ++r) y[i * 4 + r] = fmaxf((float)v[r], 0.f);
        }
        float o = ob2[0];
        for (int co = 0; co < 64; ++co) {           // weights uniform -> s_loads
            float a0 = ob1[co], a1 = 0.f;
            #pragma unroll
            for (int ci = 0; ci < 64; ci += 2) {
                a0 = fmaf(ow1[co * 64 + ci],     y[ci],     a0);
                a1 = fmaf(ow1[co * 64 + ci + 1], y[ci + 1], a1);
            }
            o = fmaf(ow2[co], fmaxf(a0 + a1, 0.f), o);
        }
        out[(size_t)bb * Tn + t] = o;
        __syncthreads();                            // SH reusable for u=1
    }
}

// ---------------------------------------------------------------------------
extern "C" void kernel_launch(void* const* d_in, const int* in_sizes, int n_in,
                              void* d_out, int out_size, void* d_ws, size_t ws_size,
                              hipStream_t stream)
{
    const float* x    = (const float*)d_in[0];
    const float* w_in = (const float*)d_in[1];
    const float* b_in = (const float*)d_in[2];
    const float* fw   = (const float*)d_in[3];
    const float* fb   = (const float*)d_in[4];
    const float* gw   = (const float*)d_in[5];
    const float* gb   = (const float*)d_in[6];
    const float* rw   = (const float*)d_in[7];
    const float* rb   = (const float*)d_in[8];
    const float* sw   = (const float*)d_in[9];
    const float* sb   = (const float*)d_in[10];
    const float* ow1  = (const float*)d_in[11];
    const float* ob1  = (const float*)d_in[12];
    const float* ow2  = (const float*)d_in[13];
    const float* ob2  = (const float*)d_in[14];
    float* out = (float*)d_out;

    const size_t n = (size_t)Bn * Tn * 64;
    _Float16* hA   = (_Float16*)d_ws;
    _Float16* hB   = hA + n;
    _Float16* wfgP = hB + n;
    _Float16* rsP  = wfgP + (size_t)Ln * 24576;
    unsigned* bar  = (unsigned*)(rsP + (size_t)Ln * 8192);

    hipMemsetAsync(bar, 0, 2 * sizeof(unsigned), stream);
    k_fused<<<dim3(512), dim3(256), 0, stream>>>(
        x, w_in, b_in, fw, gw, rw, sw, fb, gb, rb, sb,
        ow1, ob1, ow2, ob2, out, hA, hB, wfgP, rsP, bar);
}

// Round 10
// 1898.398 us; speedup vs baseline: 1.1565x; 1.0651x over previous
//
#include <hip/hip_runtime.h>
#include <math.h>

#define Bn 16
#define Tn 16384
#define Fn 32
#define Cn 64
#define Ln 10
#define ST 76   // LDS tile row stride (elements): 152B -> conflict-free patterns

typedef _Float16 v8h  __attribute__((ext_vector_type(8)));
typedef _Float16 v4h  __attribute__((ext_vector_type(4)));
typedef float    v16f __attribute__((ext_vector_type(16)));
typedef float    v4f  __attribute__((ext_vector_type(4)));

// ---------------------------------------------------------------------------
// Software grid barrier (device-scope atomics).  Cooperative launch is NOT
// stream-capturable (R5): counter + generation word in d_ws, memset each
// launch.  Deadlock-safe: amdgpu_waves_per_eu(2,2) -> VGPR<=256 -> >=8
// waves/CU -> >=2 blk/CU; LDS 38912B -> 4 blk/CU; capacity >= 512 = grid.
// ---------------------------------------------------------------------------
__device__ __forceinline__ void gbarrier(unsigned* bar, unsigned nblk, unsigned phase)
{
    __syncthreads();
    if (threadIdx.x == 0) {
        __threadfence();
        unsigned prev = __hip_atomic_fetch_add(&bar[0], 1u, __ATOMIC_ACQ_REL,
                                               __HIP_MEMORY_SCOPE_AGENT);
        if (prev == nblk - 1u) {
            __hip_atomic_store(&bar[0], 0u, __ATOMIC_RELAXED, __HIP_MEMORY_SCOPE_AGENT);
            __hip_atomic_store(&bar[1], phase, __ATOMIC_RELEASE, __HIP_MEMORY_SCOPE_AGENT);
        } else {
            while (__hip_atomic_load(&bar[1], __ATOMIC_ACQUIRE,
                                     __HIP_MEMORY_SCOPE_AGENT) < phase)
                __builtin_amdgcn_s_sleep(2);
        }
        __threadfence();
    }
    __syncthreads();
}

// ---------------------------------------------------------------------------
// Fully-fused WaveNet, one normal kernel + software barriers.
// R9 lesson: __launch_bounds__(256,2) only sets the occupancy FLOOR; the
// AMDGPU regalloc still targets the next occupancy TIER and spills to reach
// it (R6: chose 64=half of 128 cap; R9: chose 128=half of 256 cap; ~700MB
// spill stores).  Fix: amdgpu_waves_per_eu(2,2) pins min=max=2 -> full 256
// budget, no incentive to squeeze.  Also: accF/accG REUSED as the R/S
// accumulators (disjoint lifetimes) -> accumulator demand 128->64 regs,
// freeing the arch side for sk[] + staging.
//  - 512 blocks x 256 threads; block owns a 512-t span (4 tiles of 128t) in
//    one batch, XCD-sliced (j&7 = XCD), identical slice every layer.
//  - skip accumulator in REGISTERS across all 10 layers (sk[4][2][4]).
//  - 10 gbarriers replace kernel-launch drains; skip never touches HBM.
//  - last layer: hout write + R epilogue skipped.
// mfma_f32_32x32x16_f16: A[m=lane&31][k=(lane>>5)*8+j], B[k][n=lane&31],
// D: col(n)=lane&31, row(m)=(reg&3)+8*(reg>>2)+4*(lane>>5).
// ---------------------------------------------------------------------------
__global__ __launch_bounds__(256)
__attribute__((amdgpu_waves_per_eu(2, 2)))
void k_fused(
    const float* __restrict__ x,
    const float* __restrict__ w_in, const float* __restrict__ b_in,
    const float* __restrict__ fw,  const float* __restrict__ gw,
    const float* __restrict__ rw,  const float* __restrict__ sw,
    const float* __restrict__ fb,  const float* __restrict__ gb,
    const float* __restrict__ rb,  const float* __restrict__ sb,
    const float* __restrict__ ow1, const float* __restrict__ ob1,
    const float* __restrict__ ow2, const float* __restrict__ ob2,
    float* __restrict__ out,
    _Float16* __restrict__ hA, _Float16* __restrict__ hB,
    _Float16* __restrict__ wfgP, _Float16* __restrict__ rsP,
    unsigned* __restrict__ bar)
{
    __shared__ _Float16 SH[2 * 128 * ST];          // 38912B, multi-purpose
    _Float16* const P0 = SH;
    _Float16* const P1 = SH + 128 * ST;

    const int tid  = threadIdx.x;
    const int lane = tid & 63;
    const int wv   = tid >> 6;
    const int ch32 = wv & 1;
    const int ch   = ch32 * 32;         // co-half
    const int tb   = (wv >> 1) * 64;    // t-half within a 128-tile
    const int hl   = lane >> 5;
    const int ln31 = lane & 31;
    const int bb   = blockIdx.x >> 5;   // 32 blocks per batch
    const int j    = blockIdx.x & 31;
    const int tBase = ((j & 7) * 16 + (j >> 3) * 4) * 128;   // 512-t span
    const size_t hbase = (size_t)bb * Tn * 64;

    v8h zero8;
    #pragma unroll
    for (int z = 0; z < 8; ++z) zero8[z] = (_Float16)0.f;

    // coalesced tap staging: thread covers 4 x (tl, 8c) cells
    const int s_tl = tid >> 3;              // base row (0..31), rows step 32
    const int s_c  = (tid & 7) * 8;

    // ---- phase P: weight packing fp32 -> fp16 fragment order (grid-stride)
    {
        const int total1 = Ln * 24576;
        for (int gid = blockIdx.x * 256 + tid; gid < total1; gid += 512 * 256) {
            int l = gid / 24576, rem = gid % 24576;
            int chunk = rem >> 9, within = rem & 511;
            int ll = within >> 3, jj = within & 7;
            int c32 = chunk & 1, fg = (chunk >> 1) & 1;
            int kc = (chunk >> 2) & 3, tap = chunk >> 4;
            int co = c32 * 32 + (ll & 31);
            int ci = kc * 16 + (ll >> 5) * 8 + jj;
            const float* wsrc = fg ? gw : fw;
            wfgP[gid] = (_Float16)wsrc[((l * 64 + co) * 64 + ci) * 3 + tap];
        }
        const int total2 = Ln * 8192;
        for (int gid = blockIdx.x * 256 + tid; gid < total2; gid += 512 * 256) {
            int l = gid / 8192, rem = gid % 8192;
            int chunk = rem >> 9, within = rem & 511;
            int ll = within >> 3, jj = within & 7;
            int c32 = chunk & 1, rsi = (chunk >> 1) & 1, kc = chunk >> 2;
            int co = c32 * 32 + (ll & 31);
            int ci = kc * 16 + (ll >> 5) * 8 + jj;
            const float* wsrc = rsi ? sw : rw;
            rsP[gid] = (_Float16)wsrc[(l * 64 + co) * 64 + ci];
        }
    }

    // ---- phase I: input 1x1 conv -> hA for this block's 512 t.
    // One thread per t -> w_in/b_in loop-uniform -> scalar loads; stores
    // through LDS rotation -> flat contiguous global stores.
    #pragma unroll
    for (int u = 0; u < 2; ++u) {
        const int t0c = tBase + u * 256;
        const float* xp = x + ((size_t)bb * Tn + t0c + tid) * Fn;
        float xv[32];
        #pragma unroll
        for (int i = 0; i < 8; ++i) {
            v4f v = *(const v4f*)&xp[i * 4];
            xv[i*4+0] = v[0]; xv[i*4+1] = v[1]; xv[i*4+2] = v[2]; xv[i*4+3] = v[3];
        }
        #pragma unroll
        for (int c8 = 0; c8 < 8; ++c8) {
            v8h o;
            #pragma unroll
            for (int jj = 0; jj < 8; ++jj) {
                int c = c8 * 8 + jj;                // loop-uniform -> s_loads
                float a = b_in[c];
                #pragma unroll
                for (int f = 0; f < 32; ++f) a = fmaf(w_in[c * 32 + f], xv[f], a);
                o[jj] = (_Float16)a;
            }
            const int p = (c8 + tid) & 7;           // bank-rotate chunk slot
            *(v8h*)&SH[tid * 64 + p * 8] = o;
        }
        __syncthreads();
        _Float16* hp = hA + ((size_t)bb * Tn + t0c) * 64;
        #pragma unroll
        for (int it = 0; it < 8; ++it) {
            const int g = it * 256 + tid;           // flat 16B chunk index
            const int tl = g >> 3, c8 = g & 7;
            const int p = (c8 + tl) & 7;
            *(v8h*)&hp[g * 8] = *(const v8h*)&SH[tl * 64 + p * 8];
        }
        __syncthreads();
    }

    gbarrier(bar, 512, 1);                          // weights + h0 visible

    // persistent skip accumulator: [tile][nt][q], static-indexed -> 64 VGPRs
    v4h sk[4][2][4];

    const _Float16* cur = hA;
    _Float16* nxt = hB;

#define STAGE(DST, OFF) do {                                                  \
    _Pragma("unroll")                                                         \
    for (int it = 0; it < 4; ++it) {                                          \
        int tl = s_tl + it * 32;                                              \
        int tg = t0 + tl - (OFF);                                             \
        v8h v = zero8;                                                        \
        if (tg >= 0) v = *(const v8h*)&cur[hbase + (size_t)tg * 64 + s_c];    \
        *(v8h*)&(DST)[tl * ST + s_c] = v;                                     \
    } } while (0)

#define WOFF(TAP, KC, FG) (((((TAP) * 4 + (KC)) * 2 + (FG)) * 2 + ch32) * 512 + lane * 8)
#define RSOFF(KC, RSI)    ((((KC) * 2 + (RSI)) * 2 + ch32) * 512 + lane * 8)

#define MFMA_TAP(SRC, TAP) do {                                               \
    _Pragma("unroll")                                                         \
    for (int kc = 0; kc < 4; ++kc) {                                          \
        const int kof = kc * 16 + hl * 8;                                     \
        v8h aF = *(const v8h*)&wfg[WOFF(TAP, kc, 0)];                         \
        v8h aG = *(const v8h*)&wfg[WOFF(TAP, kc, 1)];                         \
        v8h b0 = *(const v8h*)&(SRC)[(tb + ln31) * ST + kof];                 \
        v8h b1 = *(const v8h*)&(SRC)[(tb + 32 + ln31) * ST + kof];            \
        accF[0] = __builtin_amdgcn_mfma_f32_32x32x16_f16(aF, b0, accF[0], 0, 0, 0); \
        accF[1] = __builtin_amdgcn_mfma_f32_32x32x16_f16(aF, b1, accF[1], 0, 0, 0); \
        accG[0] = __builtin_amdgcn_mfma_f32_32x32x16_f16(aG, b0, accG[0], 0, 0, 0); \
        accG[1] = __builtin_amdgcn_mfma_f32_32x32x16_f16(aG, b1, accG[1], 0, 0, 0); \
    } } while (0)

    #pragma unroll 1
    for (int l = 0; l < Ln; ++l) {
        const int dil = 1 << l;
        const _Float16* wfg = wfgP + (size_t)l * 24576;
        const _Float16* rs  = rsP  + (size_t)l * 8192;
        const float* fbl = fb + l * Cn;
        const float* gbl = gb + l * Cn;
        const float* rbl = rb + l * Cn;
        const float* sbl = sb + l * Cn;
        const bool last = (l == Ln - 1);

        #pragma unroll
        for (int tile = 0; tile < 4; ++tile) {
            const int t0 = tBase + tile * 128;

            // biases -> accumulator init (D row m -> c = ch + 8q + 4hl + r)
            v16f accF[2], accG[2];
            #pragma unroll
            for (int q = 0; q < 4; ++q) {
                v4f fv = *(const v4f*)&fbl[ch + 8 * q + 4 * hl];
                v4f gv = *(const v4f*)&gbl[ch + 8 * q + 4 * hl];
                #pragma unroll
                for (int r = 0; r < 4; ++r) {
                    accF[0][q * 4 + r] = fv[r]; accF[1][q * 4 + r] = fv[r];
                    accG[0][q * 4 + r] = gv[r]; accG[1][q * 4 + r] = gv[r];
                }
            }

            STAGE(P0, 2 * dil);
            __syncthreads();                        // S1: P0 ready
            STAGE(P1, dil);                         // overlap tap1 loads w/ tap0 mfma
            MFMA_TAP(P0, 0);
            __syncthreads();                        // S2: P1 ready, P0 reads done
            STAGE(P0, 0);                           // overlap tap2 loads w/ tap1 mfma
            MFMA_TAP(P1, 1);
            __syncthreads();                        // S3: P0 ready, P1 reads done
            MFMA_TAP(P0, 2);                        // P0 holds hin[t] - kept

            // act = tanh(f)*sigmoid(g) = (A-1)*rcp((A+1)*(1+B)) -> P1 scatter
            #pragma unroll
            for (int nt = 0; nt < 2; ++nt) {
                const int tl = tb + nt * 32 + ln31;
                #pragma unroll
                for (int q = 0; q < 4; ++q) {
                    v4h av;
                    #pragma unroll
                    for (int r = 0; r < 4; ++r) {
                        float f = accF[nt][q * 4 + r];
                        float g = accG[nt][q * 4 + r];
                        float A = __expf(2.f * f);
                        float B = __expf(-g);
                        float tA = A + 1.f;
                        float den = fmaf(tA, B, tA);
                        av[r] = (_Float16)((A - 1.f) * __builtin_amdgcn_rcpf(den));
                    }
                    *(v4h*)&P1[tl * ST + ch + 8 * q + 4 * hl] = av;
                }
            }
            __syncthreads();                        // S4: act done, tap2 reads done

            // accF/accG REUSED as R/S accumulators (disjoint lifetime; halves
            // accumulator register demand vs separate accR/accS arrays)
            #pragma unroll
            for (int q = 0; q < 4; ++q) {
                v4f rv = *(const v4f*)&rbl[ch + 8 * q + 4 * hl];
                v4f sv = *(const v4f*)&sbl[ch + 8 * q + 4 * hl];
                #pragma unroll
                for (int r = 0; r < 4; ++r) {
                    accF[0][q * 4 + r] = rv[r]; accF[1][q * 4 + r] = rv[r];
                    accG[0][q * 4 + r] = sv[r]; accG[1][q * 4 + r] = sv[r];
                }
            }
            #pragma unroll
            for (int kc = 0; kc < 4; ++kc) {
                const int kof = kc * 16 + hl * 8;
                v8h aR = *(const v8h*)&rs[RSOFF(kc, 0)];
                v8h aS = *(const v8h*)&rs[RSOFF(kc, 1)];
                v8h b0 = *(const v8h*)&P1[(tb + ln31) * ST + kof];
                v8h b1 = *(const v8h*)&P1[(tb + 32 + ln31) * ST + kof];
                accF[0] = __builtin_amdgcn_mfma_f32_32x32x16_f16(aR, b0, accF[0], 0, 0, 0);
                accF[1] = __builtin_amdgcn_mfma_f32_32x32x16_f16(aR, b1, accF[1], 0, 0, 0);
                accG[0] = __builtin_amdgcn_mfma_f32_32x32x16_f16(aS, b0, accG[0], 0, 0, 0);
                accG[1] = __builtin_amdgcn_mfma_f32_32x32x16_f16(aS, b1, accG[1], 0, 0, 0);
            }

            // R epilogue in-place on P0: h_new = (h + R)*0.7071 (dead last layer)
            if (!last) {
                #pragma unroll
                for (int nt = 0; nt < 2; ++nt) {
                    const int tl = tb + nt * 32 + ln31;
                    #pragma unroll
                    for (int q = 0; q < 4; ++q) {
                        _Float16* cell = &P0[tl * ST + ch + 8 * q + 4 * hl];
                        v4h hv = *(const v4h*)cell;
                        v4h hn;
                        #pragma unroll
                        for (int r = 0; r < 4; ++r)
                            hn[r] = (_Float16)(((float)hv[r] + accF[nt][q * 4 + r]) * 0.7071f);
                        *(v4h*)cell = hn;
                    }
                }
            }

            // skip accumulation IN REGISTERS (no HBM RMW)
            #pragma unroll
            for (int nt = 0; nt < 2; ++nt)
                #pragma unroll
                for (int q = 0; q < 4; ++q) {
                    v4h sn;
                    #pragma unroll
                    for (int r = 0; r < 4; ++r) {
                        float v = accG[nt][q * 4 + r];
                        if (l) v += (float)sk[tile][nt][q][r];
                        sn[r] = (_Float16)v;
                    }
                    sk[tile][nt][q] = sn;
                }
            __syncthreads();                        // S5: P0 = hout tile complete

            // hout coalesced store from P0 (dead for last layer)
            if (!last) {
                #pragma unroll
                for (int it = 0; it < 4; ++it) {
                    int tl = s_tl + it * 32;
                    *(v8h*)&nxt[hbase + (size_t)(t0 + tl) * 64 + s_c] =
                        *(const v8h*)&P0[tl * ST + s_c];
                }
            }
            __syncthreads();                        // S6: P0/P1 reusable next tile
        }

        if (!last) {
            gbarrier(bar, 512, (unsigned)(l + 2));  // layer complete device-wide
            _Float16* tmp = nxt; nxt = (_Float16*)cur; cur = tmp;
        }
    }
#undef STAGE
#undef MFMA_TAP
#undef WOFF
#undef RSOFF

    // ---- phase O: skip regs -> LDS transpose -> 2-layer MLP -> out ----
    // Per pass: 2 tiles (256 t); SH stride 68 halfs breaks bank aliasing.
    #pragma unroll
    for (int u = 0; u < 2; ++u) {
        #pragma unroll
        for (int tl2 = 0; tl2 < 2; ++tl2) {
            const int tile = u * 2 + tl2;
            #pragma unroll
            for (int nt = 0; nt < 2; ++nt)
                #pragma unroll
                for (int q = 0; q < 4; ++q) {
                    const int row = tl2 * 128 + tb + nt * 32 + ln31;
                    *(v4h*)&SH[row * 68 + ch + 8 * q + 4 * hl] = sk[tile][nt][q];
                }
        }
        __syncthreads();
        const int t = tBase + u * 256 + tid;        // one t per thread
        float y[64];
        #pragma unroll
        for (int i = 0; i < 16; ++i) {
            v4h v = *(const v4h*)&SH[tid * 68 + i * 4];
            #pragma unroll
            for (int r = 0; r < 4; ++r) y[i * 4 + r] = fmaxf((float)v[r], 0.f);
        }
        float o = ob2[0];
        for (int co = 0; co < 64; ++co) {           // weights uniform -> s_loads
            float a0 = ob1[co], a1 = 0.f;
            #pragma unroll
            for (int ci = 0; ci < 64; ci += 2) {
                a0 = fmaf(ow1[co * 64 + ci],     y[ci],     a0);
                a1 = fmaf(ow1[co * 64 + ci + 1], y[ci + 1], a1);
            }
            o = fmaf(ow2[co], fmaxf(a0 + a1, 0.f), o);
        }
        out[(size_t)bb * Tn + t] = o;
        __syncthreads();                            // SH reusable for u=1
    }
}

// ---------------------------------------------------------------------------
extern "C" void kernel_launch(void* const* d_in, const int* in_sizes, int n_in,
                              void* d_out, int out_size, void* d_ws, size_t ws_size,
                              hipStream_t stream)
{
    const float* x    = (const float*)d_in[0];
    const float* w_in = (const float*)d_in[1];
    const float* b_in = (const float*)d_in[2];
    const float* fw   = (const float*)d_in[3];
    const float* fb   = (const float*)d_in[4];
    const float* gw   = (const float*)d_in[5];
    const float* gb   = (const float*)d_in[6];
    const float* rw   = (const float*)d_in[7];
    const float* rb   = (const float*)d_in[8];
    const float* sw   = (const float*)d_in[9];
    const float* sb   = (const float*)d_in[10];
    const float* ow1  = (const float*)d_in[11];
    const float* ob1  = (const float*)d_in[12];
    const float* ow2  = (const float*)d_in[13];
    const float* ob2  = (const float*)d_in[14];
    float* out = (float*)d_out;

    const size_t n = (size_t)Bn * Tn * 64;
    _Float16* hA   = (_Float16*)d_ws;
    _Float16* hB   = hA + n;
    _Float16* wfgP = hB + n;
    _Float16* rsP  = wfgP + (size_t)Ln * 24576;
    unsigned* bar  = (unsigned*)(rsP + (size_t)Ln * 8192);

    hipMemsetAsync(bar, 0, 2 * sizeof(unsigned), stream);
    k_fused<<<dim3(512), dim3(256), 0, stream>>>(
        x, w_in, b_in, fw, gw, rw, sw, fb, gb, rb, sb,
        ow1, ob1, ow2, ob2, out, hA, hB, wfgP, rsP, bar);
}